// Round 1
// baseline (978.565 us; speedup 1.0000x reference)
//
#include <hip/hip_runtime.h>
#include <math.h>

// LocalSTD: out = sqrt( G*x^2 - (G*x)^2 + 1e-6 ), G = 11x11 Gaussian (sigma=1),
// separable. x: [16,64,256,256] fp32 = 1024 images of 256x256.
//
// R4: shuffle-based horizontal exchange (no LDS, no fences, no bank conflicts),
// packed-fp32 vertical pass (v_pk_fma_f32 via ext_vector <4 x float>), and
// 2x grid (2048 blocks, 32-row bands) for full 32-wave/CU occupancy at <=64 VGPR.
//
// Wave = 64 lanes x 4 cols = full 256-col row. Vertical 11-tap from an 11-row
// float4 register ring (prefetch-by-1). Horizontal 11-tap needs lanes i-1/i+1's
// float4 and one float from lanes i-2/i+2: 10 ds_bpermute per stream via
// __shfl_up/__shfl_down, boundary lanes zeroed by mask-multiply (image border
// is zero-padded, and wave edges coincide with image edges).

#define W        256
#define IMG_PIX  (W * W)
#define BANDH    32          // output rows per wave; block = 4 waves = 128 rows

// normalized 1D Gaussian sigma=1 (2D kernel = outer product, sums factorize)
#define GW0 1.4867195e-06f   // |d|=5
#define GW1 1.3383023e-04f   // |d|=4
#define GW2 4.4318485e-03f   // |d|=3
#define GW3 5.3990965e-02f   // |d|=2
#define GW4 2.4197072e-01f   // |d|=1
#define GW5 3.9894228e-01f   // center

typedef float f4 __attribute__((ext_vector_type(4)));

__device__ __forceinline__ f4 vfma(float g, f4 a, f4 c) {
    f4 gv = {g, g, g, g};
    return __builtin_elementwise_fma(gv, a, c);   // -> v_pk_fma_f32 pairs
}

__device__ __forceinline__ f4 load_row(const float* __restrict__ xi, int gr, int c) {
    if ((unsigned)gr < (unsigned)W)
        return *(const f4*)(xi + (size_t)gr * W + c);
    return (f4){0.f, 0.f, 0.f, 0.f};
}

__device__ __forceinline__ f4 shfl_up1(f4 v) {
    f4 r;
    r.x = __shfl_up(v.x, 1);
    r.y = __shfl_up(v.y, 1);
    r.z = __shfl_up(v.z, 1);
    r.w = __shfl_up(v.w, 1);
    return r;
}
__device__ __forceinline__ f4 shfl_dn1(f4 v) {
    f4 r;
    r.x = __shfl_down(v.x, 1);
    r.y = __shfl_down(v.y, 1);
    r.z = __shfl_down(v.z, 1);
    r.w = __shfl_down(v.w, 1);
    return r;
}

// Horizontal 11-tap for this lane's 4 cols of one stream. v = own float4
// (cols c..c+3). Halo via wave shuffles; boundary lanes (== image border)
// zeroed by mask-multiply (mu1: lane>=1, mu2: lane>=2, md1: lane<=62,
// md2: lane<=61). Shuffled garbage at the edge is the lane's own finite
// value, so *0.0f is safe.
__device__ __forceinline__ void hpass(f4 v, float mu1, float mu2,
                                      float md1, float md2, float h[4]) {
    f4 L = shfl_up1(v);                      // lane i-1: cols c-4..c-1
    float eL = __shfl_up(v.w, 2) * mu2;      // lane i-2 col c-5
    f4 R = shfl_dn1(v);                      // lane i+1: cols c+4..c+7
    float eR = __shfl_down(v.x, 2) * md2;    // lane i+2 col c+8
    L *= mu1;
    R *= md1;
    float F[14] = { eL,  L.x, L.y, L.z, L.w,
                    v.x, v.y, v.z, v.w,
                    R.x, R.y, R.z, R.w,  eR };   // F[k] = col c-5+k
    #pragma unroll
    for (int j = 0; j < 4; ++j) {
        float s = GW5 * F[j + 5];
        s = fmaf(GW4, F[j + 4] + F[j + 6],  s);
        s = fmaf(GW3, F[j + 3] + F[j + 7],  s);
        s = fmaf(GW2, F[j + 2] + F[j + 8],  s);
        s = fmaf(GW1, F[j + 1] + F[j + 9],  s);
        s = fmaf(GW0, F[j + 0] + F[j + 10], s);
        h[j] = s;
    }
}

// Ring slot of input row q is (q - r0 + 5) mod 11. Invariant at entry of step K
// (output row grow, (grow-r0)%11 == K): ring holds rows grow-6..grow+4, and
// pf = row grow+5 (prefetched last step). Step: insert pf (slot (K+10)%11,
// evicting dead row grow-6), issue prefetch of row grow+6, v-pass (packed fp32,
// squares recomputed -- saves 44 VGPRs over a squares ring), h-pass, store.
template<int K>
__device__ __forceinline__ void row_step(const float* __restrict__ xi,
                                         float* __restrict__ oi,
                                         f4 (&xw)[11], f4& pf,
                                         int c, int grow,
                                         float mu1, float mu2,
                                         float md1, float md2) {
    constexpr int SN = (K + 10) % 11;
    xw[SN] = pf;                                   // ring: rows grow-5..grow+5
    f4 pn = load_row(xi, grow + 6, c);             // prefetch for step K+1

    // vertical 11-tap (symmetric pairs) on packed fp32
    constexpr int SC = (K + 5) % 11;
    f4 xc = xw[SC];
    f4 v1 = xc * GW5;
    f4 v2 = (xc * xc) * GW5;
    #define VPAIR(D, G) { constexpr int A_ = (K + 5 - (D)) % 11;                 \
                          constexpr int B_ = (K + 5 + (D)) % 11;                 \
                          f4 xa_ = xw[A_], xb_ = xw[B_];                         \
                          v1 = vfma(G, xa_ + xb_, v1);                           \
                          f4 sq_ = __builtin_elementwise_fma(xb_, xb_, xa_*xa_); \
                          v2 = vfma(G, sq_, v2); }
    VPAIR(1, GW4) VPAIR(2, GW3) VPAIR(3, GW2) VPAIR(4, GW1) VPAIR(5, GW0)
    #undef VPAIR

    // horizontal passes kept sequential (stream 1 then stream 2) to bound
    // live-range pressure under the 64-VGPR / 8-wave-per-SIMD cap.
    float h1[4], h2[4];
    hpass(v1, mu1, mu2, md1, md2, h1);
    hpass(v2, mu1, mu2, md1, md2, h2);

    f4 o;
    o.x = sqrtf(fmaf(-h1[0], h1[0], h2[0]) + 1e-6f);
    o.y = sqrtf(fmaf(-h1[1], h1[1], h2[1]) + 1e-6f);
    o.z = sqrtf(fmaf(-h1[2], h1[2], h2[2]) + 1e-6f);
    o.w = sqrtf(fmaf(-h1[3], h1[3], h2[3]) + 1e-6f);
    *(f4*)(oi + (size_t)grow * W + c) = o;

    pf = pn;
}

__global__ __launch_bounds__(256, 8) void
local_std_kernel(const float* __restrict__ x, float* __restrict__ out) {
    const int t    = threadIdx.x;
    const int wv   = t >> 6;
    const int lane = t & 63;
    const int bid  = blockIdx.x;
    const int img  = bid >> 1;                  // 2 blocks per image
    const int half = bid & 1;
    const float* xi = x   + (size_t)img * IMG_PIX;
    float*       oi = out + (size_t)img * IMG_PIX;

    const int c  = lane << 2;                   // this lane's 4 columns
    const int r0 = half * (W / 2) + wv * BANDH; // band start (wave-private)

    // boundary masks for the shuffle halo (loop-invariant -> SGPR conditions)
    const float mu1 = (lane >= 1)  ? 1.f : 0.f;
    const float mu2 = (lane >= 2)  ? 1.f : 0.f;
    const float md1 = (lane <= 62) ? 1.f : 0.f;
    const float md2 = (lane <= 61) ? 1.f : 0.f;

    // warm-up: rows r0-5..r0+4 into slots 0..9; slot 10 is filled at step 0.
    f4 xw[11];
    #pragma unroll
    for (int i = 0; i < 10; ++i)
        xw[i] = load_row(xi, r0 - 5 + i, c);
    xw[10] = (f4){0.f, 0.f, 0.f, 0.f};
    f4 pf = load_row(xi, r0 + 5, c);

    // sweep 32 output rows; unroll-by-11 keeps ring/template indices static.
    // Outer loop kept rolled (uniform branches) to bound I-cache footprint.
    #pragma unroll 1
    for (int ii = 0; ii < 3; ++ii) {
        const int base = ii * 11;
        #define STEP(k) if (base + (k) < BANDH) \
            row_step<(k)>(xi, oi, xw, pf, c, r0 + base + (k), mu1, mu2, md1, md2);
        STEP(0) STEP(1) STEP(2) STEP(3) STEP(4) STEP(5)
        STEP(6) STEP(7) STEP(8) STEP(9) STEP(10)
        #undef STEP
    }
}

extern "C" void kernel_launch(void* const* d_in, const int* in_sizes, int n_in,
                              void* d_out, int out_size, void* d_ws, size_t ws_size,
                              hipStream_t stream) {
    const float* x  = (const float*)d_in[0];
    float* out      = (float*)d_out;
    const int n_img = in_sizes[0] / IMG_PIX;    // 16*64 = 1024
    local_std_kernel<<<dim3(n_img * 2), 256, 0, stream>>>(x, out);
}

// Round 2
// 451.625 us; speedup vs baseline: 2.1668x; 2.1668x over previous
//
#include <hip/hip_runtime.h>
#include <math.h>

// LocalSTD: out = sqrt( G*x^2 - (G*x)^2 + 1e-6 ), G = 11x11 Gaussian (sigma=1),
// separable. x: [16,64,256,256] fp32 = 1024 images of 256x256.
//
// R5: R4's shuffle-based horizontal exchange (no LDS, no fences, no bank
// conflicts) + packed-fp32 vertical pass, but with __launch_bounds__(256,4).
// R4's (256,8) capped the allocator at 32 VGPRs -> the 11-row float4 ring
// spilled to scratch (FETCH 153MB->1.55GB, dur 165->689us). The ring needs
// ~60 VGPRs live; (256,4) caps at 128, no spill, and still allows 5-6
// waves/SIMD at the ~80 VGPRs this kernel actually uses.
//
// Wave = 64 lanes x 4 cols = full 256-col row. Vertical 11-tap from an 11-row
// float4 register ring (prefetch-by-1). Horizontal 11-tap halo via 10
// ds_bpermute per stream (__shfl_up/__shfl_down); boundary lanes zeroed by
// mask-multiply (image border is zero-padded; wave edges == image edges).

#define W        256
#define IMG_PIX  (W * W)
#define BANDH    32          // output rows per wave; block = 4 waves = 128 rows

// normalized 1D Gaussian sigma=1 (2D kernel = outer product, sums factorize)
#define GW0 1.4867195e-06f   // |d|=5
#define GW1 1.3383023e-04f   // |d|=4
#define GW2 4.4318485e-03f   // |d|=3
#define GW3 5.3990965e-02f   // |d|=2
#define GW4 2.4197072e-01f   // |d|=1
#define GW5 3.9894228e-01f   // center

typedef float f4 __attribute__((ext_vector_type(4)));

__device__ __forceinline__ f4 vfma(float g, f4 a, f4 c) {
    f4 gv = {g, g, g, g};
    return __builtin_elementwise_fma(gv, a, c);   // -> v_pk_fma_f32 pairs
}

__device__ __forceinline__ f4 load_row(const float* __restrict__ xi, int gr, int c) {
    if ((unsigned)gr < (unsigned)W)
        return *(const f4*)(xi + (size_t)gr * W + c);
    return (f4){0.f, 0.f, 0.f, 0.f};
}

__device__ __forceinline__ f4 shfl_up1(f4 v) {
    f4 r;
    r.x = __shfl_up(v.x, 1);
    r.y = __shfl_up(v.y, 1);
    r.z = __shfl_up(v.z, 1);
    r.w = __shfl_up(v.w, 1);
    return r;
}
__device__ __forceinline__ f4 shfl_dn1(f4 v) {
    f4 r;
    r.x = __shfl_down(v.x, 1);
    r.y = __shfl_down(v.y, 1);
    r.z = __shfl_down(v.z, 1);
    r.w = __shfl_down(v.w, 1);
    return r;
}

// Horizontal 11-tap for this lane's 4 cols of one stream. v = own float4
// (cols c..c+3). Halo via wave shuffles; boundary lanes (== image border)
// zeroed by mask-multiply (mu1: lane>=1, mu2: lane>=2, md1: lane<=62,
// md2: lane<=61). Shuffled garbage at the edge is the lane's own finite
// value, so *0.0f is safe.
__device__ __forceinline__ void hpass(f4 v, float mu1, float mu2,
                                      float md1, float md2, float h[4]) {
    f4 L = shfl_up1(v);                      // lane i-1: cols c-4..c-1
    float eL = __shfl_up(v.w, 2) * mu2;      // lane i-2 col c-5
    f4 R = shfl_dn1(v);                      // lane i+1: cols c+4..c+7
    float eR = __shfl_down(v.x, 2) * md2;    // lane i+2 col c+8
    L *= mu1;
    R *= md1;
    float F[14] = { eL,  L.x, L.y, L.z, L.w,
                    v.x, v.y, v.z, v.w,
                    R.x, R.y, R.z, R.w,  eR };   // F[k] = col c-5+k
    #pragma unroll
    for (int j = 0; j < 4; ++j) {
        float s = GW5 * F[j + 5];
        s = fmaf(GW4, F[j + 4] + F[j + 6],  s);
        s = fmaf(GW3, F[j + 3] + F[j + 7],  s);
        s = fmaf(GW2, F[j + 2] + F[j + 8],  s);
        s = fmaf(GW1, F[j + 1] + F[j + 9],  s);
        s = fmaf(GW0, F[j + 0] + F[j + 10], s);
        h[j] = s;
    }
}

// Ring slot of input row q is (q - r0 + 5) mod 11. Invariant at entry of step K
// (output row grow, (grow-r0)%11 == K): ring holds rows grow-6..grow+4, and
// pf = row grow+5 (prefetched last step). Step: insert pf (slot (K+10)%11,
// evicting dead row grow-6), issue prefetch of row grow+6, v-pass (packed fp32,
// squares recomputed -- saves 44 VGPRs over a squares ring), h-pass, store.
template<int K>
__device__ __forceinline__ void row_step(const float* __restrict__ xi,
                                         float* __restrict__ oi,
                                         f4 (&xw)[11], f4& pf,
                                         int c, int grow,
                                         float mu1, float mu2,
                                         float md1, float md2) {
    constexpr int SN = (K + 10) % 11;
    xw[SN] = pf;                                   // ring: rows grow-5..grow+5
    f4 pn = load_row(xi, grow + 6, c);             // prefetch for step K+1

    // vertical 11-tap (symmetric pairs) on packed fp32
    constexpr int SC = (K + 5) % 11;
    f4 xc = xw[SC];
    f4 v1 = xc * GW5;
    f4 v2 = (xc * xc) * GW5;
    #define VPAIR(D, G) { constexpr int A_ = (K + 5 - (D)) % 11;                 \
                          constexpr int B_ = (K + 5 + (D)) % 11;                 \
                          f4 xa_ = xw[A_], xb_ = xw[B_];                         \
                          v1 = vfma(G, xa_ + xb_, v1);                           \
                          f4 sq_ = __builtin_elementwise_fma(xb_, xb_, xa_*xa_); \
                          v2 = vfma(G, sq_, v2); }
    VPAIR(1, GW4) VPAIR(2, GW3) VPAIR(3, GW2) VPAIR(4, GW1) VPAIR(5, GW0)
    #undef VPAIR

    // horizontal passes kept sequential (stream 1 then stream 2) to bound
    // live-range pressure.
    float h1[4], h2[4];
    hpass(v1, mu1, mu2, md1, md2, h1);
    hpass(v2, mu1, mu2, md1, md2, h2);

    f4 o;
    o.x = sqrtf(fmaf(-h1[0], h1[0], h2[0]) + 1e-6f);
    o.y = sqrtf(fmaf(-h1[1], h1[1], h2[1]) + 1e-6f);
    o.z = sqrtf(fmaf(-h1[2], h1[2], h2[2]) + 1e-6f);
    o.w = sqrtf(fmaf(-h1[3], h1[3], h2[3]) + 1e-6f);
    *(f4*)(oi + (size_t)grow * W + c) = o;

    pf = pn;
}

__global__ __launch_bounds__(256, 4) void
local_std_kernel(const float* __restrict__ x, float* __restrict__ out) {
    const int t    = threadIdx.x;
    const int wv   = t >> 6;
    const int lane = t & 63;
    const int bid  = blockIdx.x;
    const int img  = bid >> 1;                  // 2 blocks per image
    const int half = bid & 1;
    const float* xi = x   + (size_t)img * IMG_PIX;
    float*       oi = out + (size_t)img * IMG_PIX;

    const int c  = lane << 2;                   // this lane's 4 columns
    const int r0 = half * (W / 2) + wv * BANDH; // band start (wave-private)

    // boundary masks for the shuffle halo (loop-invariant)
    const float mu1 = (lane >= 1)  ? 1.f : 0.f;
    const float mu2 = (lane >= 2)  ? 1.f : 0.f;
    const float md1 = (lane <= 62) ? 1.f : 0.f;
    const float md2 = (lane <= 61) ? 1.f : 0.f;

    // warm-up: rows r0-5..r0+4 into slots 0..9; slot 10 is filled at step 0.
    f4 xw[11];
    #pragma unroll
    for (int i = 0; i < 10; ++i)
        xw[i] = load_row(xi, r0 - 5 + i, c);
    xw[10] = (f4){0.f, 0.f, 0.f, 0.f};
    f4 pf = load_row(xi, r0 + 5, c);

    // sweep 32 output rows; unroll-by-11 keeps ring/template indices static.
    // Outer loop kept rolled (uniform branches) to bound I-cache footprint.
    #pragma unroll 1
    for (int ii = 0; ii < 3; ++ii) {
        const int base = ii * 11;
        #define STEP(k) if (base + (k) < BANDH) \
            row_step<(k)>(xi, oi, xw, pf, c, r0 + base + (k), mu1, mu2, md1, md2);
        STEP(0) STEP(1) STEP(2) STEP(3) STEP(4) STEP(5)
        STEP(6) STEP(7) STEP(8) STEP(9) STEP(10)
        #undef STEP
    }
}

extern "C" void kernel_launch(void* const* d_in, const int* in_sizes, int n_in,
                              void* d_out, int out_size, void* d_ws, size_t ws_size,
                              hipStream_t stream) {
    const float* x  = (const float*)d_in[0];
    float* out      = (float*)d_out;
    const int n_img = in_sizes[0] / IMG_PIX;    // 16*64 = 1024
    local_std_kernel<<<dim3(n_img * 2), 256, 0, stream>>>(x, out);
}